// Round 3
// baseline (709.617 us; speedup 1.0000x reference)
//
#include <hip/hip_runtime.h>
#include <hip/hip_fp16.h>
#include <math.h>

#define NN 100000
#define EE 3200000
#define ETOT (EE + NN)
#define NEG_SLOPE 0.2f
#define DMAX 96
#define CHUNK 4096
#define NB0 ((ETOT + CHUNK - 1) / CHUNK)  // 806
#define RB 391                            // 256 * 391 >= NN
#define CAP 16384                         // window per coarse bucket (expect ~12.9k, sigma ~114)
#define GEMM1B (2 * 1563)                 // gemm1 blocks (2 head-pairs x 1563 row-tiles)

typedef _Float16 half8 __attribute__((ext_vector_type(8)));
typedef _Float16 half4v __attribute__((ext_vector_type(4)));
typedef float floatx4 __attribute__((ext_vector_type(4)));

// ---------------- helpers ----------------
__device__ __forceinline__ float wsum64(float v) {
#pragma unroll
  for (int o = 32; o; o >>= 1) v += __shfl_xor(v, o);
  return v;
}
__device__ __forceinline__ float lrelu(float v) { return v > 0.f ? v : NEG_SLOPE * v; }
__device__ __forceinline__ float elu1(float v) { return v > 0.f ? v : expm1f(v); }

// ---------------- init: window cursors ----------------
__global__ void k_init(int* __restrict__ ccur) {
  ccur[threadIdx.x] = threadIdx.x * CAP;
}

// ---------------- k_front: pass1 edge bucketize + W2t prep + GEMM1, one launch ----------
// block ranges: [0,NB0) edge chunks; [NB0,NB0+64) W2t prep; [NB0+64, NB0+64+GEMM1B) gemm1.
// gemm1 reads W1 directly (fp32, 64KB, L2-hot) so it has no intra-launch dependency.
// h1h is written HEAD-MAJOR: h1h[head][node][64] for per-head gather passes.
__global__ __launch_bounds__(256) void k_front(const int* __restrict__ ei,
                                               int* __restrict__ ccur,
                                               unsigned* __restrict__ ebuf,
                                               const float* __restrict__ W1,
                                               const float* __restrict__ W2,
                                               _Float16* __restrict__ W2t,
                                               const float* __restrict__ x,
                                               const float* __restrict__ a_src,
                                               const float* __restrict__ a_dst,
                                               _Float16* __restrict__ h1h,
                                               float* __restrict__ as_out,
                                               float* __restrict__ ad_out) {
  __shared__ __align__(16) char smem[52224];
  const int b = blockIdx.x;
  const int t = threadIdx.x;
  if (b < NB0) {
    // ---- edge bucketize (pass1) ----
    unsigned* vv = (unsigned*)smem;                        // 16384 B
    unsigned short* cbv = (unsigned short*)(smem + 16384); // 8192 B
    int* h = (int*)(smem + 24576);                         // 1024 B
    int* cur = (int*)(smem + 25600);                       // 1024 B
    h[t] = 0;
    __syncthreads();
    int base = b * CHUNK;
    int lim = base + CHUNK; if (lim > ETOT) lim = ETOT;
    int cnt = lim - base;
    for (int i = t; i < cnt; i += 256) {
      int e = base + i;
      int s, d;
      if (e < EE) { s = ei[e]; d = ei[EE + e]; } else { s = e - EE; d = s; }
      unsigned cb = (unsigned)d / (unsigned)RB;
      unsigned dloc = (unsigned)d - cb * (unsigned)RB;
      vv[i] = (dloc << 17) | (unsigned)s;
      cbv[i] = (unsigned short)cb;
      atomicAdd(&h[cb], 1);
    }
    __syncthreads();
    if (h[t]) cur[t] = atomicAdd(&ccur[t], h[t]);
    __syncthreads();
    for (int i = t; i < cnt; i += 256) {
      int cb = cbv[i];
      int pos = atomicAdd(&cur[cb], 1);
      ebuf[pos] = vv[i];
    }
    return;
  }
  if (b < NB0 + 64) {
    // ---- W2t prep: W2t[n][k] = W2[k][n], 64x256 fp16 ----
    int idx = (b - NB0) * 256 + t;  // 0..16383
    int n = idx >> 8, k = idx & 255;
    W2t[idx] = (_Float16)W2[k * 64 + n];
    return;
  }
  // ---- GEMM1 (MFMA fp16): h1h + as1/ad1 from x@W1 ----
  const int bb = b - NB0 - 64;
  const int bx = bb & 1;   // head pair
  const int by = bb >> 1;
  _Float16 (*As)[136] = (_Float16(*)[136])smem;            // 64 x 136 = 17408 B
  _Float16 (*Wt)[136] = (_Float16(*)[136])(smem + 17408);  // 128 x 136 = 34816 B
  const int row0 = by * 64;
  // stage A (fp32 -> fp16): 64 x 128
#pragma unroll
  for (int i = 0; i < 8; ++i) {
    int idx = i * 256 + t;
    int r = idx >> 5;
    int c4 = (idx & 31) * 4;
    int gr = row0 + r;
    float4 f = make_float4(0.f, 0.f, 0.f, 0.f);
    if (gr < NN) f = *(const float4*)(x + (size_t)gr * 128 + c4);
    half4v hh; hh[0] = (_Float16)f.x; hh[1] = (_Float16)f.y; hh[2] = (_Float16)f.z; hh[3] = (_Float16)f.w;
    *(half4v*)&As[r][c4] = hh;
  }
  // stage Wt[r][k] = W1[k][bx*128 + r] (transpose while converting)
#pragma unroll
  for (int i = 0; i < 16; ++i) {
    int j = i * 256 + t;          // 0..4095
    int k = j >> 5;               // 0..127
    int r4 = (j & 31) * 4;        // 0..124
    float4 f = *(const float4*)(W1 + (size_t)k * 256 + bx * 128 + r4);
    Wt[r4 + 0][k] = (_Float16)f.x;
    Wt[r4 + 1][k] = (_Float16)f.y;
    Wt[r4 + 2][k] = (_Float16)f.z;
    Wt[r4 + 3][k] = (_Float16)f.w;
  }
  __syncthreads();

  const int wid = t >> 6, lane = t & 63;
  const int m16 = lane & 15, quad = lane >> 4;
  floatx4 acc[8];
#pragma unroll
  for (int nt = 0; nt < 8; ++nt) acc[nt] = (floatx4){0.f, 0.f, 0.f, 0.f};
#pragma unroll
  for (int ks = 0; ks < 4; ++ks) {
    half8 av = *(half8*)&As[wid * 16 + m16][ks * 32 + quad * 8];
#pragma unroll
    for (int nt = 0; nt < 8; ++nt) {
      half8 bv = *(half8*)&Wt[nt * 16 + m16][ks * 32 + quad * 8];
      acc[nt] = __builtin_amdgcn_mfma_f32_16x16x32_f16(av, bv, acc[nt], 0, 0, 0);
    }
  }
  float asr[8], adr[8];
#pragma unroll
  for (int nt = 0; nt < 8; ++nt) {
    asr[nt] = a_src[bx * 128 + nt * 16 + m16];
    adr[nt] = a_dst[bx * 128 + nt * 16 + m16];
  }
#pragma unroll
  for (int r = 0; r < 4; ++r) {
    int gr = row0 + wid * 16 + quad * 4 + r;
    bool ok = gr < NN;
#pragma unroll
    for (int hp = 0; hp < 2; ++hp) {
      float ps = 0.f, pd = 0.f;
#pragma unroll
      for (int j = 0; j < 4; ++j) {
        ps = fmaf(acc[hp * 4 + j][r], asr[hp * 4 + j], ps);
        pd = fmaf(acc[hp * 4 + j][r], adr[hp * 4 + j], pd);
      }
#pragma unroll
      for (int o = 1; o < 16; o <<= 1) { ps += __shfl_xor(ps, o); pd += __shfl_xor(pd, o); }
      if (ok && m16 == 0) {
        as_out[gr * 4 + bx * 2 + hp] = ps;
        ad_out[gr * 4 + bx * 2 + hp] = pd;
      }
    }
    if (ok) {
#pragma unroll
      for (int nt = 0; nt < 8; ++nt) {
        int head = bx * 2 + (nt >> 2);
        int dim = (nt & 3) * 16 + m16;
        h1h[((size_t)head * NN + gr) * 64 + dim] = (_Float16)acc[nt][r];
      }
    }
  }
}

// ---------------- pass2: per-bucket exact placement via LDS cursors; emits offs+deg+csr ----
__global__ __launch_bounds__(256) void k_pass2(const unsigned* __restrict__ ebuf,
                                               const int* __restrict__ ccur,
                                               int* __restrict__ offs,
                                               int* __restrict__ degarr,
                                               int* __restrict__ csr) {
  __shared__ unsigned ed[CAP];
  __shared__ int hist[RB];
  __shared__ int cur[RB];
  int b = blockIdx.x, t = threadIdx.x;
  int d0 = b * RB;
  int rb = NN - d0; if (rb > RB) rb = RB;
  int w0 = b * CAP;
  int cnt = ccur[b] - w0;
  if (cnt > CAP) cnt = CAP;  // statistical impossibility guard
  for (int j = t; j < rb; j += 256) hist[j] = 0;
  __syncthreads();
  for (int i = t; i < cnt; i += 256) {
    unsigned v = ebuf[w0 + i];
    ed[i] = v;
    atomicAdd(&hist[v >> 17], 1);
  }
  __syncthreads();
  if (t == 0) {
    int run = w0;
    for (int j = 0; j < rb; ++j) { cur[j] = run; run += hist[j]; }
  }
  __syncthreads();
  for (int j = t; j < rb; j += 256) {
    offs[d0 + j] = cur[j];
    degarr[d0 + j] = hist[j];
  }
  __syncthreads();
  for (int i = t; i < cnt; i += 256) {
    unsigned v = ed[i];
    int pos = atomicAdd(&cur[v >> 17], 1);
    csr[pos] = (int)(v & 0x1FFFFu);
  }
}

// ---------------- fused attention layer 1, ONE HEAD per launch -> h1e slice ----------------
// Per-head pass shrinks the gather table to 12.8 MB (head-major h1h) to raise L2 hit rate.
// alpha recomputed per pass from a_s/a_d (1.6 MB, L2-resident). 8 lanes per edge x half8
// = 128 B row per edge-group; 8 edges (1 KB) per wave-load instruction, 4 in flight.
__global__ __launch_bounds__(256) void k_attn1h(const int* __restrict__ offs,
                                                const int* __restrict__ degarr,
                                                const int* __restrict__ csr_src,
                                                const float* __restrict__ a_s,
                                                const float* __restrict__ a_d,
                                                const _Float16* __restrict__ h1h,
                                                const float* __restrict__ b1,
                                                _Float16* __restrict__ h1e,
                                                int head) {
  __shared__ float alp[4][DMAX];
  __shared__ int sidx[4][DMAX];
  const int wid = threadIdx.x >> 6;
  const int n = blockIdx.x * 4 + wid;
  const int lane = threadIdx.x & 63;
  const int beg = offs[n], deg = degarr[n];
  const float adh = a_d[n * 4 + head];
  float sm = 0.f;
  for (int d = lane; d < deg; d += 64) {
    int s = csr_src[beg + d];
    float e = __expf(lrelu(a_s[s * 4 + head] + adh));
    sm += e;
    if (d < DMAX) { sidx[wid][d] = s; alp[wid][d] = e; }
  }
  sm = wsum64(sm);
  const float inv = 1.f / sm;
  const int dlim = deg < DMAX ? deg : DMAX;
  for (int d = lane; d < dlim; d += 64) alp[wid][d] *= inv;
  const int g = lane >> 3;      // edge group 0..7
  const int sub = lane & 7;     // dims sub*8 .. sub*8+7
  const _Float16* __restrict__ hb = h1h + (size_t)head * NN * 64 + sub * 8;
  float acc[8];
#pragma unroll
  for (int j = 0; j < 8; ++j) acc[j] = 0.f;
  int d = 0;
  for (; d + 32 <= dlim; d += 32) {  // 4 x 1KB wave-loads in flight
    int ss[4]; float ww[4];
#pragma unroll
    for (int u = 0; u < 4; ++u) {
      int idx = d + u * 8 + g;
      ss[u] = sidx[wid][idx];
      ww[u] = alp[wid][idx];
    }
    half8 rr[4];
#pragma unroll
    for (int u = 0; u < 4; ++u)
      rr[u] = *(const half8*)(hb + (size_t)ss[u] * 64);
#pragma unroll
    for (int u = 0; u < 4; ++u) {
#pragma unroll
      for (int j = 0; j < 8; ++j)
        acc[j] = fmaf((float)rr[u][j], ww[u], acc[j]);
    }
  }
  for (; d + 8 <= dlim; d += 8) {
    int idx = d + g;
    int s = sidx[wid][idx];
    float w = alp[wid][idx];
    half8 r = *(const half8*)(hb + (size_t)s * 64);
#pragma unroll
    for (int j = 0; j < 8; ++j) acc[j] = fmaf((float)r[j], w, acc[j]);
  }
  if (d < dlim) {  // tail 1..7 edges: inactive groups get weight 0
    int idx = d + g;
    bool v = idx < dlim;
    int s = sidx[wid][v ? idx : d];
    float w = v ? alp[wid][idx] : 0.f;
    half8 r = *(const half8*)(hb + (size_t)s * 64);
#pragma unroll
    for (int j = 0; j < 8; ++j) acc[j] = fmaf((float)r[j], w, acc[j]);
  }
  if (deg > DMAX && g == 0) {  // overflow fallback: never in practice
    for (int dd = DMAX; dd < deg; ++dd) {
      int s = csr_src[beg + dd];
      float w = __expf(lrelu(a_s[s * 4 + head] + adh)) * inv;
      half8 r = *(const half8*)(hb + (size_t)s * 64);
#pragma unroll
      for (int j = 0; j < 8; ++j) acc[j] = fmaf((float)r[j], w, acc[j]);
    }
  }
  // reduce across the 8 edge-groups (lane bits 3,4,5)
#pragma unroll
  for (int j = 0; j < 8; ++j) {
    acc[j] += __shfl_xor(acc[j], 8);
    acc[j] += __shfl_xor(acc[j], 16);
    acc[j] += __shfl_xor(acc[j], 32);
  }
  if (g == 0) {
    const int c = head * 64 + sub * 8;
    half8 o;
#pragma unroll
    for (int j = 0; j < 8; ++j) o[j] = (_Float16)elu1(acc[j] + b1[c + j]);
    *(half8*)(h1e + (size_t)n * 256 + c) = o;
  }
}

// ---------------- GEMM2 (MFMA fp16): h2h + as2/ad2 from h1e@W2 ----------------
__global__ __launch_bounds__(256) void k_gemm2m(const _Float16* __restrict__ h1e,
                                                const _Float16* __restrict__ W2t,
                                                const float* __restrict__ a_src,
                                                const float* __restrict__ a_dst,
                                                _Float16* __restrict__ h2h,
                                                float* __restrict__ as_out,
                                                float* __restrict__ ad_out) {
  __shared__ _Float16 As2[64][136];
  __shared__ _Float16 Wt2[64][264];
  const int by = blockIdx.x;
  const int tid = threadIdx.x;
  const int row0 = by * 64;
#pragma unroll
  for (int i = 0; i < 8; ++i) {
    int idx = i * 256 + tid;
    int r = idx >> 5;
    int g = idx & 31;
    *(half8*)&Wt2[r][g * 8] = *(const half8*)(W2t + (size_t)r * 256 + g * 8);
  }
  const int wid = tid >> 6, lane = tid & 63;
  const int m16 = lane & 15, quad = lane >> 4;
  floatx4 acc[4];
#pragma unroll
  for (int nt = 0; nt < 4; ++nt) acc[nt] = (floatx4){0.f, 0.f, 0.f, 0.f};

  for (int kc = 0; kc < 2; ++kc) {
#pragma unroll
    for (int i = 0; i < 4; ++i) {
      int idx = i * 256 + tid;
      int r = idx >> 4;
      int g = idx & 15;
      int gr = row0 + r;
      half8 v = {0, 0, 0, 0, 0, 0, 0, 0};
      if (gr < NN) v = *(const half8*)(h1e + (size_t)gr * 256 + kc * 128 + g * 8);
      *(half8*)&As2[r][g * 8] = v;
    }
    __syncthreads();
#pragma unroll
    for (int ks = 0; ks < 4; ++ks) {
      half8 av = *(half8*)&As2[wid * 16 + m16][ks * 32 + quad * 8];
#pragma unroll
      for (int nt = 0; nt < 4; ++nt) {
        half8 bv = *(half8*)&Wt2[nt * 16 + m16][kc * 128 + ks * 32 + quad * 8];
        acc[nt] = __builtin_amdgcn_mfma_f32_16x16x32_f16(av, bv, acc[nt], 0, 0, 0);
      }
    }
    __syncthreads();
  }
  float asr[4], adr[4];
#pragma unroll
  for (int nt = 0; nt < 4; ++nt) {
    asr[nt] = a_src[nt * 16 + m16];
    adr[nt] = a_dst[nt * 16 + m16];
  }
#pragma unroll
  for (int r = 0; r < 4; ++r) {
    float ps = 0.f, pd = 0.f;
#pragma unroll
    for (int nt = 0; nt < 4; ++nt) {
      ps = fmaf(acc[nt][r], asr[nt], ps);
      pd = fmaf(acc[nt][r], adr[nt], pd);
    }
#pragma unroll
    for (int o = 1; o < 16; o <<= 1) { ps += __shfl_xor(ps, o); pd += __shfl_xor(pd, o); }
    int gr = row0 + wid * 16 + quad * 4 + r;
    if (gr < NN) {
      if (m16 == 0) { as_out[gr] = ps; ad_out[gr] = pd; }
#pragma unroll
      for (int nt = 0; nt < 4; ++nt)
        h2h[(size_t)gr * 64 + nt * 16 + m16] = (_Float16)acc[nt][r];
    }
  }
}

// ---------------- fused attention layer 2 + final linear ----------------
__global__ __launch_bounds__(256) void k_attn2(const int* __restrict__ offs,
                                               const int* __restrict__ degarr,
                                               const int* __restrict__ csr_src,
                                               const float* __restrict__ a_s,
                                               const float* __restrict__ a_d,
                                               const _Float16* __restrict__ h2h,
                                               const float* __restrict__ b2,
                                               const float* __restrict__ lin_w,
                                               const float* __restrict__ lin_b,
                                               float* __restrict__ out) {
  __shared__ float alpha2[4][DMAX];
  __shared__ int sidx2[4][DMAX];
  const int wid = threadIdx.x >> 6;
  const int n = blockIdx.x * 4 + wid;
  const int lane = threadIdx.x & 63;
  const int beg = offs[n], deg = degarr[n];
  const float adn = a_d[n];
  float sm = 0.f;
  for (int d = lane; d < deg; d += 64) {
    int s = csr_src[beg + d];
    float e = __expf(lrelu(a_s[s] + adn));
    sm += e;
    if (d < DMAX) { sidx2[wid][d] = s; alpha2[wid][d] = e; }
  }
  sm = wsum64(sm);
  const float inv = 1.f / sm;
  const int dlim = deg < DMAX ? deg : DMAX;
  for (int d = lane; d < dlim; d += 64) alpha2[wid][d] *= inv;
  const int g = lane >> 4;       // edge group 0..3
  const int sub = lane & 15;     // dims sub*4 .. sub*4+3
  const _Float16* __restrict__ hb = h2h + sub * 4;
  float a0 = 0.f, a1 = 0.f, a2 = 0.f, a3 = 0.f;
  int d = 0;
  for (; d + 8 <= dlim; d += 8) {
    int i0 = d + g, i1 = d + 4 + g;
    int s0 = sidx2[wid][i0], s1 = sidx2[wid][i1];
    float w0 = alpha2[wid][i0], w1 = alpha2[wid][i1];
    half4v r0 = *(const half4v*)(hb + (size_t)s0 * 64);
    half4v r1 = *(const half4v*)(hb + (size_t)s1 * 64);
    a0 = fmaf((float)r0[0], w0, a0); a1 = fmaf((float)r0[1], w0, a1);
    a2 = fmaf((float)r0[2], w0, a2); a3 = fmaf((float)r0[3], w0, a3);
    a0 = fmaf((float)r1[0], w1, a0); a1 = fmaf((float)r1[1], w1, a1);
    a2 = fmaf((float)r1[2], w1, a2); a3 = fmaf((float)r1[3], w1, a3);
  }
  if (d + 4 <= dlim) {
    int i0 = d + g;
    int s0 = sidx2[wid][i0];
    float w0 = alpha2[wid][i0];
    half4v r0 = *(const half4v*)(hb + (size_t)s0 * 64);
    a0 = fmaf((float)r0[0], w0, a0); a1 = fmaf((float)r0[1], w0, a1);
    a2 = fmaf((float)r0[2], w0, a2); a3 = fmaf((float)r0[3], w0, a3);
    d += 4;
  }
  if (d < dlim) {  // remainder 1..3 edges: inactive groups get weight 0
    int idx = d + g;
    bool v = idx < dlim;
    int s = sidx2[wid][v ? idx : d];
    float w = v ? alpha2[wid][idx] : 0.f;
    half4v r = *(const half4v*)(hb + (size_t)s * 64);
    a0 = fmaf((float)r[0], w, a0); a1 = fmaf((float)r[1], w, a1);
    a2 = fmaf((float)r[2], w, a2); a3 = fmaf((float)r[3], w, a3);
  }
  if (deg > DMAX && g == 0) {  // overflow fallback: never in practice
    for (int dd = DMAX; dd < deg; ++dd) {
      int s = csr_src[beg + dd];
      float w = __expf(lrelu(a_s[s] + adn)) * inv;
      half4v r = *(const half4v*)(hb + (size_t)s * 64);
      a0 = fmaf((float)r[0], w, a0); a1 = fmaf((float)r[1], w, a1);
      a2 = fmaf((float)r[2], w, a2); a3 = fmaf((float)r[3], w, a3);
    }
  }
  // combine the 4 edge-groups (lane bits 4 and 5)
  a0 += __shfl_xor(a0, 16); a1 += __shfl_xor(a1, 16);
  a2 += __shfl_xor(a2, 16); a3 += __shfl_xor(a3, 16);
  a0 += __shfl_xor(a0, 32); a1 += __shfl_xor(a1, 32);
  a2 += __shfl_xor(a2, 32); a3 += __shfl_xor(a3, 32);
  const int c = sub * 4;
  float4 bb = *(const float4*)(b2 + c);
  float o0 = elu1(a0 + bb.x);
  float o1 = elu1(a1 + bb.y);
  float o2 = elu1(a2 + bb.z);
  float o3 = elu1(a3 + bb.w);
  float4 lw0 = *(const float4*)(lin_w + c * 2);
  float4 lw1 = *(const float4*)(lin_w + c * 2 + 4);
  float p0 = o0 * lw0.x + o1 * lw0.z + o2 * lw1.x + o3 * lw1.z;
  float p1 = o0 * lw0.y + o1 * lw0.w + o2 * lw1.y + o3 * lw1.w;
  p0 = wsum64(p0) * 0.25f;  // each dim-partial appears in 4 lane-groups
  p1 = wsum64(p1) * 0.25f;
  if (lane == 0) {
    out[n * 2 + 0] = p0 + lin_b[0];
    out[n * 2 + 1] = p1 + lin_b[1];
  }
}

// ---------------- launch ----------------
extern "C" void kernel_launch(void* const* d_in, const int* in_sizes, int n_in,
                              void* d_out, int out_size, void* d_ws, size_t ws_size,
                              hipStream_t stream) {
  const float* x      = (const float*)d_in[0];
  const int*   ei     = (const int*)d_in[1];
  const float* W1     = (const float*)d_in[2];
  const float* a_src1 = (const float*)d_in[3];
  const float* a_dst1 = (const float*)d_in[4];
  const float* b1     = (const float*)d_in[5];
  const float* W2     = (const float*)d_in[6];
  const float* a_src2 = (const float*)d_in[7];
  const float* a_dst2 = (const float*)d_in[8];
  const float* b2     = (const float*)d_in[9];
  const float* lin_w  = (const float*)d_in[10];
  const float* lin_b  = (const float*)d_in[11];
  float* outp = (float*)d_out;

  char* w = (char*)d_ws;
  _Float16* h1h = (_Float16*)(w + 0);            // 51,200,000 (head-major [4][NN][64])
  _Float16* h1e = (_Float16*)(w + 51200000);     // 51,200,000
  _Float16* h2h = (_Float16*)(w + 102400000);    // 12,800,000
  _Float16* W2t = (_Float16*)(w + 115265536);    // 32,768
  float*  as1 = (float*)(w + 115298304);         // 1,600,000
  float*  ad1 = (float*)(w + 116898304);         // 1,600,000
  float*  as2 = (float*)(w + 118498304);         // 400,000
  float*  ad2 = (float*)(w + 118898304);         // 400,000
  int*    offs = (int*)(w + 119298304);          // 400,000
  int*    degarr = (int*)(w + 119698304);        // 400,000
  int*    ccur = (int*)(w + 120098304);          // 1,024
  unsigned* ebuf = (unsigned*)(w + 120099328);   // 256*CAP*4 = 16,777,216
  int*    csr = (int*)(w + 136876544);           // 256*CAP*4 = 16,777,216

  // CSR pass1 + W2t prep + GEMM1 in one launch (overlap bucketize with GEMM)
  k_init<<<1, 256, 0, stream>>>(ccur);
  k_front<<<NB0 + 64 + GEMM1B, 256, 0, stream>>>(ei, ccur, ebuf, W1, W2, W2t,
                                                 x, a_src1, a_dst1, h1h, as1, ad1);
  k_pass2<<<256, 256, 0, stream>>>(ebuf, ccur, offs, degarr, csr);

  // layer 1 attention: 4 per-head passes (12.8 MB gather table each)
  for (int h = 0; h < 4; ++h)
    k_attn1h<<<NN / 4, 256, 0, stream>>>(offs, degarr, csr, as1, ad1, h1h, b1, h1e, h);

  // layer 2
  k_gemm2m<<<1563, 256, 0, stream>>>(h1e, W2t, a_src2, a_dst2, h2h, as2, ad2);
  k_attn2<<<NN / 4, 256, 0, stream>>>(offs, degarr, csr, as2, ad2, h2h, b2, lin_w, lin_b, outp);
}

// Round 4
// 594.210 us; speedup vs baseline: 1.1942x; 1.1942x over previous
//
#include <hip/hip_runtime.h>
#include <hip/hip_fp16.h>
#include <math.h>

#define NN 100000
#define EE 3200000
#define ETOT (EE + NN)
#define NEG_SLOPE 0.2f
#define DMAX 96
#define CHUNK 4096
#define NB0 ((ETOT + CHUNK - 1) / CHUNK)  // 806
#define RB 391                            // 256 * 391 >= NN
#define CAP 16384                         // window per coarse bucket (expect ~12.9k, sigma ~114)
#define PREPB 391                         // xh/as1/ad1 prep blocks appended to pass1

typedef _Float16 half8 __attribute__((ext_vector_type(8)));
typedef _Float16 half4v __attribute__((ext_vector_type(4)));
typedef _Float16 half2v __attribute__((ext_vector_type(2)));
typedef float floatx4 __attribute__((ext_vector_type(4)));

// ---------------- helpers ----------------
__device__ __forceinline__ float wsum64(float v) {
#pragma unroll
  for (int o = 32; o; o >>= 1) v += __shfl_xor(v, o);
  return v;
}
__device__ __forceinline__ float lrelu(float v) { return v > 0.f ? v : NEG_SLOPE * v; }
__device__ __forceinline__ float elu1(float v) { return v > 0.f ? v : expm1f(v); }

// ---------------- init: window cursors ----------------
__global__ void k_init(int* __restrict__ ccur) {
  ccur[threadIdx.x] = threadIdx.x * CAP;
}

// ---------------- pass1: edge bucketize + weight prep + xh/as1/ad1 prep ----------------
// blocks [0,NB0): bucketize; [NB0,NB0+192): W1t/W2t fp16 transposes;
// [NB0+192, NB0+192+PREPB): xh = fp16(x), as1/ad1 = x . (W1^T a) per head (exact by linearity).
__global__ __launch_bounds__(256) void k_pass1(const int* __restrict__ ei,
                                               int* __restrict__ ccur,
                                               unsigned* __restrict__ ebuf,
                                               const float* __restrict__ W1,
                                               const float* __restrict__ W2,
                                               _Float16* __restrict__ W1t,
                                               _Float16* __restrict__ W2t,
                                               const float* __restrict__ x,
                                               const float* __restrict__ a_src1,
                                               const float* __restrict__ a_dst1,
                                               _Float16* __restrict__ xh,
                                               float* __restrict__ as1,
                                               float* __restrict__ ad1) {
  __shared__ __align__(16) char smem[26624];
  const int b = blockIdx.x;
  const int t = threadIdx.x;
  if (b < NB0) {
    unsigned* vv = (unsigned*)smem;                        // 16384 B
    unsigned short* cbv = (unsigned short*)(smem + 16384); // 8192 B
    int* h = (int*)(smem + 24576);                         // 1024 B
    int* cur = (int*)(smem + 25600);                       // 1024 B
    h[t] = 0;
    __syncthreads();
    int base = b * CHUNK;
    int lim = base + CHUNK; if (lim > ETOT) lim = ETOT;
    int cnt = lim - base;
    for (int i = t; i < cnt; i += 256) {
      int e = base + i;
      int s, d;
      if (e < EE) { s = ei[e]; d = ei[EE + e]; } else { s = e - EE; d = s; }
      unsigned cb = (unsigned)d / (unsigned)RB;
      unsigned dloc = (unsigned)d - cb * (unsigned)RB;
      vv[i] = (dloc << 17) | (unsigned)s;
      cbv[i] = (unsigned short)cb;
      atomicAdd(&h[cb], 1);
    }
    __syncthreads();
    if (h[t]) cur[t] = atomicAdd(&ccur[t], h[t]);
    __syncthreads();
    for (int i = t; i < cnt; i += 256) {
      int cb = cbv[i];
      int pos = atomicAdd(&cur[cb], 1);
      ebuf[pos] = vv[i];
    }
    return;
  }
  if (b < NB0 + 192) {
    // weight prep: W1t[n][k] = W1[k][n] (32768), W2t[n][k] = W2[k][n] (16384)
    int idx = (b - NB0) * 256 + t;
    if (idx < 32768) {
      int n = idx >> 7, k = idx & 127;
      W1t[idx] = (_Float16)W1[k * 256 + n];
    } else {
      int j = idx - 32768;
      int n = j >> 8, k = j & 255;
      W2t[j] = (_Float16)W2[k * 64 + n];
    }
    return;
  }
  // ---- prep: vs/vd = W1^T a (per head), then per-node xh + as1/ad1 ----
  float* vs = (float*)smem;        // 512 floats
  float* vd = vs + 512;            // 512 floats
  for (int i = t; i < 512; i += 256) {
    int h = i >> 7, k = i & 127;
    const float* wrow = W1 + (size_t)k * 256 + h * 64;
    float ss = 0.f, dd = 0.f;
#pragma unroll 8
    for (int d2 = 0; d2 < 64; ++d2) {
      float wv = wrow[d2];
      ss = fmaf(wv, a_src1[h * 64 + d2], ss);
      dd = fmaf(wv, a_dst1[h * 64 + d2], dd);
    }
    vs[i] = ss; vd[i] = dd;
  }
  __syncthreads();
  const int lane = t & 63;
  const int gw = (b - NB0 - 192) * 4 + (t >> 6);  // 0 .. 4*PREPB-1
  for (int n = gw; n < NN; n += 4 * PREPB) {
    float2 xv = *(const float2*)(x + (size_t)n * 128 + lane * 2);
    half2v hx; hx[0] = (_Float16)xv.x; hx[1] = (_Float16)xv.y;
    *(half2v*)(xh + (size_t)n * 128 + lane * 2) = hx;
    float p[8];
#pragma unroll
    for (int h = 0; h < 4; ++h) {
      p[h]     = xv.x * vs[h * 128 + lane * 2] + xv.y * vs[h * 128 + lane * 2 + 1];
      p[4 + h] = xv.x * vd[h * 128 + lane * 2] + xv.y * vd[h * 128 + lane * 2 + 1];
    }
#pragma unroll
    for (int j = 0; j < 8; ++j) p[j] = wsum64(p[j]);
    if (lane == 0) {
      *(float4*)(as1 + n * 4) = make_float4(p[0], p[1], p[2], p[3]);
      *(float4*)(ad1 + n * 4) = make_float4(p[4], p[5], p[6], p[7]);
    }
  }
}

// ---------------- pass2: per-bucket exact placement via LDS cursors; emits offs+deg+csr ----
__global__ __launch_bounds__(256) void k_pass2(const unsigned* __restrict__ ebuf,
                                               const int* __restrict__ ccur,
                                               int* __restrict__ offs,
                                               int* __restrict__ degarr,
                                               int* __restrict__ csr) {
  __shared__ unsigned ed[CAP];
  __shared__ int hist[RB];
  __shared__ int cur[RB];
  int b = blockIdx.x, t = threadIdx.x;
  int d0 = b * RB;
  int rb = NN - d0; if (rb > RB) rb = RB;
  int w0 = b * CAP;
  int cnt = ccur[b] - w0;
  if (cnt > CAP) cnt = CAP;  // statistical impossibility guard
  for (int j = t; j < rb; j += 256) hist[j] = 0;
  __syncthreads();
  for (int i = t; i < cnt; i += 256) {
    unsigned v = ebuf[w0 + i];
    ed[i] = v;
    atomicAdd(&hist[v >> 17], 1);
  }
  __syncthreads();
  if (t == 0) {
    int run = w0;
    for (int j = 0; j < rb; ++j) { cur[j] = run; run += hist[j]; }
  }
  __syncthreads();
  for (int j = t; j < rb; j += 256) {
    offs[d0 + j] = cur[j];
    degarr[d0 + j] = hist[j];
  }
  __syncthreads();
  for (int i = t; i < cnt; i += 256) {
    unsigned v = ed[i];
    int pos = atomicAdd(&cur[v >> 17], 1);
    csr[pos] = (int)(v & 0x1FFFFu);
  }
}

// ---------------- agg1: per-dst softmax + aggregate fp16(x) rows, all 4 heads ----------
// One wave per dst. Gather table = xh (25.6 MB, 256 B rows); one row read serves all heads.
// 16 lanes/edge x half8 (16 B) = full 256 B row; 4 edge-groups; 2 edges in flight.
// acc[4 heads][8 dims] fp32 per lane; output agg[n][4][128] fp16.
__global__ __launch_bounds__(256) void k_agg1(const int* __restrict__ offs,
                                              const int* __restrict__ degarr,
                                              const int* __restrict__ csr_src,
                                              const float* __restrict__ a_s,
                                              const float* __restrict__ a_d,
                                              const _Float16* __restrict__ xh,
                                              _Float16* __restrict__ agg) {
  __shared__ __align__(16) float alp[4][DMAX][4];
  __shared__ int sidx[4][DMAX];
  const int wid = threadIdx.x >> 6;
  const int n = blockIdx.x * 4 + wid;
  const int lane = threadIdx.x & 63;
  const int beg = offs[n], deg = degarr[n];
  const float4 ad = *(const float4*)(a_d + n * 4);
  float4 sm = make_float4(0.f, 0.f, 0.f, 0.f);
  for (int d = lane; d < deg; d += 64) {
    int s = csr_src[beg + d];
    float4 as = *(const float4*)(a_s + s * 4);
    float e0 = __expf(lrelu(as.x + ad.x));
    float e1 = __expf(lrelu(as.y + ad.y));
    float e2 = __expf(lrelu(as.z + ad.z));
    float e3 = __expf(lrelu(as.w + ad.w));
    sm.x += e0; sm.y += e1; sm.z += e2; sm.w += e3;
    if (d < DMAX) {
      sidx[wid][d] = s;
      *(float4*)&alp[wid][d][0] = make_float4(e0, e1, e2, e3);
    }
  }
  sm.x = wsum64(sm.x); sm.y = wsum64(sm.y); sm.z = wsum64(sm.z); sm.w = wsum64(sm.w);
  const float4 inv4 = make_float4(1.f / sm.x, 1.f / sm.y, 1.f / sm.z, 1.f / sm.w);
  const int dlim = deg < DMAX ? deg : DMAX;
  for (int d = lane; d < dlim; d += 64) {
    float4 a = *(float4*)&alp[wid][d][0];
    a.x *= inv4.x; a.y *= inv4.y; a.z *= inv4.z; a.w *= inv4.w;
    *(float4*)&alp[wid][d][0] = a;
  }
  const int g = lane >> 4;       // edge group 0..3
  const int sub = lane & 15;     // dims sub*8 .. sub*8+7 (16 x 8 = 128)
  const _Float16* __restrict__ hb = xh + sub * 8;
  float acc[4][8];
#pragma unroll
  for (int h = 0; h < 4; ++h)
#pragma unroll
    for (int j = 0; j < 8; ++j) acc[h][j] = 0.f;
  int d = 0;
  for (; d + 8 <= dlim; d += 8) {
    int i0 = d + g, i1 = d + 4 + g;
    int s0 = sidx[wid][i0], s1 = sidx[wid][i1];
    float4 w0 = *(float4*)&alp[wid][i0][0];
    float4 w1 = *(float4*)&alp[wid][i1][0];
    half8 r0 = *(const half8*)(hb + (size_t)s0 * 128);
    half8 r1 = *(const half8*)(hb + (size_t)s1 * 128);
#pragma unroll
    for (int j = 0; j < 8; ++j) {
      float f0 = (float)r0[j], f1 = (float)r1[j];
      acc[0][j] = fmaf(f0, w0.x, acc[0][j]);
      acc[1][j] = fmaf(f0, w0.y, acc[1][j]);
      acc[2][j] = fmaf(f0, w0.z, acc[2][j]);
      acc[3][j] = fmaf(f0, w0.w, acc[3][j]);
      acc[0][j] = fmaf(f1, w1.x, acc[0][j]);
      acc[1][j] = fmaf(f1, w1.y, acc[1][j]);
      acc[2][j] = fmaf(f1, w1.z, acc[2][j]);
      acc[3][j] = fmaf(f1, w1.w, acc[3][j]);
    }
  }
  if (d + 4 <= dlim) {
    int i0 = d + g;
    int s0 = sidx[wid][i0];
    float4 w0 = *(float4*)&alp[wid][i0][0];
    half8 r0 = *(const half8*)(hb + (size_t)s0 * 128);
#pragma unroll
    for (int j = 0; j < 8; ++j) {
      float f0 = (float)r0[j];
      acc[0][j] = fmaf(f0, w0.x, acc[0][j]);
      acc[1][j] = fmaf(f0, w0.y, acc[1][j]);
      acc[2][j] = fmaf(f0, w0.z, acc[2][j]);
      acc[3][j] = fmaf(f0, w0.w, acc[3][j]);
    }
    d += 4;
  }
  if (d < dlim) {  // remainder 1..3 edges: inactive groups get weight 0
    int idx = d + g;
    bool v = idx < dlim;
    int s = sidx[wid][v ? idx : d];
    float4 w0 = *(float4*)&alp[wid][v ? idx : d][0];
    if (!v) { w0.x = 0.f; w0.y = 0.f; w0.z = 0.f; w0.w = 0.f; }
    half8 r0 = *(const half8*)(hb + (size_t)s * 128);
#pragma unroll
    for (int j = 0; j < 8; ++j) {
      float f0 = (float)r0[j];
      acc[0][j] = fmaf(f0, w0.x, acc[0][j]);
      acc[1][j] = fmaf(f0, w0.y, acc[1][j]);
      acc[2][j] = fmaf(f0, w0.z, acc[2][j]);
      acc[3][j] = fmaf(f0, w0.w, acc[3][j]);
    }
  }
  if (deg > DMAX) {  // overflow fallback: never in practice
    for (int dd = DMAX + g; dd < deg; dd += 4) {
      int s = csr_src[beg + dd];
      float4 as = *(const float4*)(a_s + s * 4);
      float w0x = __expf(lrelu(as.x + ad.x)) * inv4.x;
      float w0y = __expf(lrelu(as.y + ad.y)) * inv4.y;
      float w0z = __expf(lrelu(as.z + ad.z)) * inv4.z;
      float w0w = __expf(lrelu(as.w + ad.w)) * inv4.w;
      half8 r0 = *(const half8*)(hb + (size_t)s * 128);
#pragma unroll
      for (int j = 0; j < 8; ++j) {
        float f0 = (float)r0[j];
        acc[0][j] = fmaf(f0, w0x, acc[0][j]);
        acc[1][j] = fmaf(f0, w0y, acc[1][j]);
        acc[2][j] = fmaf(f0, w0z, acc[2][j]);
        acc[3][j] = fmaf(f0, w0w, acc[3][j]);
      }
    }
  }
  // reduce across the 4 edge-groups (lane bits 4,5)
#pragma unroll
  for (int h = 0; h < 4; ++h)
#pragma unroll
    for (int j = 0; j < 8; ++j) {
      acc[h][j] += __shfl_xor(acc[h][j], 16);
      acc[h][j] += __shfl_xor(acc[h][j], 32);
    }
  if (g == 0) {
#pragma unroll
    for (int h = 0; h < 4; ++h) {
      half8 o;
#pragma unroll
      for (int j = 0; j < 8; ++j) o[j] = (_Float16)acc[h][j];
      *(half8*)(agg + ((size_t)n * 4 + h) * 128 + sub * 8) = o;
    }
  }
}

// ---------------- fused GEMMs: h1e = elu(agg@W1 + b1); h2h/as2/ad2 = h1e@W2 ----------
// h1e exists only as a 64x256 LDS tile per block; h1h/h1e never hit HBM.
// B-operands read register-direct from L1-hot W1t (64KB) / W2t (32KB).
__global__ __launch_bounds__(256) void k_gemmAgg2(const _Float16* __restrict__ agg,
                                                  const _Float16* __restrict__ W1t,
                                                  const _Float16* __restrict__ W2t,
                                                  const float* __restrict__ b1,
                                                  const float* __restrict__ a_src2,
                                                  const float* __restrict__ a_dst2,
                                                  _Float16* __restrict__ h2h,
                                                  float* __restrict__ as_out,
                                                  float* __restrict__ ad_out) {
  __shared__ _Float16 h1eT[64][264];
  const int tid = threadIdx.x;
  const int row0 = blockIdx.x * 64;
  const int wid = tid >> 6, lane = tid & 63;
  const int m16 = lane & 15, quad = lane >> 4;
  // GEMM1: out1[64][256] = agg @ W1 (per head), A register-direct from global
  floatx4 acc1[4][4];
#pragma unroll
  for (int h = 0; h < 4; ++h)
#pragma unroll
    for (int nt = 0; nt < 4; ++nt) acc1[h][nt] = (floatx4){0.f, 0.f, 0.f, 0.f};
  const size_t arow = (size_t)(row0 + wid * 16 + m16) * 512;
#pragma unroll
  for (int h = 0; h < 4; ++h) {
#pragma unroll
    for (int ks = 0; ks < 4; ++ks) {
      half8 av = *(const half8*)(agg + arow + h * 128 + ks * 32 + quad * 8);
#pragma unroll
      for (int nt = 0; nt < 4; ++nt) {
        half8 bv = *(const half8*)(W1t + (size_t)(h * 64 + nt * 16 + m16) * 128 + ks * 32 + quad * 8);
        acc1[h][nt] = __builtin_amdgcn_mfma_f32_16x16x32_f16(av, bv, acc1[h][nt], 0, 0, 0);
      }
    }
  }
  // epilogue 1: bias + elu -> LDS tile
#pragma unroll
  for (int h = 0; h < 4; ++h)
#pragma unroll
    for (int nt = 0; nt < 4; ++nt) {
      float bb = b1[h * 64 + nt * 16 + m16];
#pragma unroll
      for (int r = 0; r < 4; ++r)
        h1eT[wid * 16 + quad * 4 + r][h * 64 + nt * 16 + m16] = (_Float16)elu1(acc1[h][nt][r] + bb);
    }
  __syncthreads();
  // GEMM2: h2[64][64] = h1eT @ W2
  floatx4 acc2[4];
#pragma unroll
  for (int nt = 0; nt < 4; ++nt) acc2[nt] = (floatx4){0.f, 0.f, 0.f, 0.f};
#pragma unroll
  for (int ks = 0; ks < 8; ++ks) {
    half8 av = *(const half8*)&h1eT[wid * 16 + m16][ks * 32 + quad * 8];
#pragma unroll
    for (int nt = 0; nt < 4; ++nt) {
      half8 bv = *(const half8*)(W2t + (size_t)(nt * 16 + m16) * 256 + ks * 32 + quad * 8);
      acc2[nt] = __builtin_amdgcn_mfma_f32_16x16x32_f16(av, bv, acc2[nt], 0, 0, 0);
    }
  }
  float asr[4], adr[4];
#pragma unroll
  for (int nt = 0; nt < 4; ++nt) {
    asr[nt] = a_src2[nt * 16 + m16];
    adr[nt] = a_dst2[nt * 16 + m16];
  }
#pragma unroll
  for (int r = 0; r < 4; ++r) {
    float ps = 0.f, pd = 0.f;
#pragma unroll
    for (int nt = 0; nt < 4; ++nt) {
      ps = fmaf(acc2[nt][r], asr[nt], ps);
      pd = fmaf(acc2[nt][r], adr[nt], pd);
    }
#pragma unroll
    for (int o = 1; o < 16; o <<= 1) { ps += __shfl_xor(ps, o); pd += __shfl_xor(pd, o); }
    int gr = row0 + wid * 16 + quad * 4 + r;
    if (gr < NN) {
      if (m16 == 0) { as_out[gr] = ps; ad_out[gr] = pd; }
#pragma unroll
      for (int nt = 0; nt < 4; ++nt)
        h2h[(size_t)gr * 64 + nt * 16 + m16] = (_Float16)acc2[nt][r];
    }
  }
}

// ---------------- fused attention layer 2 + final linear ----------------
__global__ __launch_bounds__(256) void k_attn2(const int* __restrict__ offs,
                                               const int* __restrict__ degarr,
                                               const int* __restrict__ csr_src,
                                               const float* __restrict__ a_s,
                                               const float* __restrict__ a_d,
                                               const _Float16* __restrict__ h2h,
                                               const float* __restrict__ b2,
                                               const float* __restrict__ lin_w,
                                               const float* __restrict__ lin_b,
                                               float* __restrict__ out) {
  __shared__ float alpha2[4][DMAX];
  __shared__ int sidx2[4][DMAX];
  const int wid = threadIdx.x >> 6;
  const int n = blockIdx.x * 4 + wid;
  const int lane = threadIdx.x & 63;
  const int beg = offs[n], deg = degarr[n];
  const float adn = a_d[n];
  float sm = 0.f;
  for (int d = lane; d < deg; d += 64) {
    int s = csr_src[beg + d];
    float e = __expf(lrelu(a_s[s] + adn));
    sm += e;
    if (d < DMAX) { sidx2[wid][d] = s; alpha2[wid][d] = e; }
  }
  sm = wsum64(sm);
  const float inv = 1.f / sm;
  const int dlim = deg < DMAX ? deg : DMAX;
  for (int d = lane; d < dlim; d += 64) alpha2[wid][d] *= inv;
  const int g = lane >> 4;       // edge group 0..3
  const int sub = lane & 15;     // dims sub*4 .. sub*4+3
  const _Float16* __restrict__ hb = h2h + sub * 4;
  float a0 = 0.f, a1 = 0.f, a2 = 0.f, a3 = 0.f;
  int d = 0;
  for (; d + 8 <= dlim; d += 8) {
    int i0 = d + g, i1 = d + 4 + g;
    int s0 = sidx2[wid][i0], s1 = sidx2[wid][i1];
    float w0 = alpha2[wid][i0], w1 = alpha2[wid][i1];
    half4v r0 = *(const half4v*)(hb + (size_t)s0 * 64);
    half4v r1 = *(const half4v*)(hb + (size_t)s1 * 64);
    a0 = fmaf((float)r0[0], w0, a0); a1 = fmaf((float)r0[1], w0, a1);
    a2 = fmaf((float)r0[2], w0, a2); a3 = fmaf((float)r0[3], w0, a3);
    a0 = fmaf((float)r1[0], w1, a0); a1 = fmaf((float)r1[1], w1, a1);
    a2 = fmaf((float)r1[2], w1, a2); a3 = fmaf((float)r1[3], w1, a3);
  }
  if (d + 4 <= dlim) {
    int i0 = d + g;
    int s0 = sidx2[wid][i0];
    float w0 = alpha2[wid][i0];
    half4v r0 = *(const half4v*)(hb + (size_t)s0 * 64);
    a0 = fmaf((float)r0[0], w0, a0); a1 = fmaf((float)r0[1], w0, a1);
    a2 = fmaf((float)r0[2], w0, a2); a3 = fmaf((float)r0[3], w0, a3);
    d += 4;
  }
  if (d < dlim) {  // remainder 1..3 edges: inactive groups get weight 0
    int idx = d + g;
    bool v = idx < dlim;
    int s = sidx2[wid][v ? idx : d];
    float w = v ? alpha2[wid][idx] : 0.f;
    half4v r = *(const half4v*)(hb + (size_t)s * 64);
    a0 = fmaf((float)r[0], w, a0); a1 = fmaf((float)r[1], w, a1);
    a2 = fmaf((float)r[2], w, a2); a3 = fmaf((float)r[3], w, a3);
  }
  if (deg > DMAX && g == 0) {  // overflow fallback: never in practice
    for (int dd = DMAX; dd < deg; ++dd) {
      int s = csr_src[beg + dd];
      float w = __expf(lrelu(a_s[s] + adn)) * inv;
      half4v r = *(const half4v*)(hb + (size_t)s * 64);
      a0 = fmaf((float)r[0], w, a0); a1 = fmaf((float)r[1], w, a1);
      a2 = fmaf((float)r[2], w, a2); a3 = fmaf((float)r[3], w, a3);
    }
  }
  // combine the 4 edge-groups (lane bits 4 and 5)
  a0 += __shfl_xor(a0, 16); a1 += __shfl_xor(a1, 16);
  a2 += __shfl_xor(a2, 16); a3 += __shfl_xor(a3, 16);
  a0 += __shfl_xor(a0, 32); a1 += __shfl_xor(a1, 32);
  a2 += __shfl_xor(a2, 32); a3 += __shfl_xor(a3, 32);
  const int c = sub * 4;
  float4 bb = *(const float4*)(b2 + c);
  float o0 = elu1(a0 + bb.x);
  float o1 = elu1(a1 + bb.y);
  float o2 = elu1(a2 + bb.z);
  float o3 = elu1(a3 + bb.w);
  float4 lw0 = *(const float4*)(lin_w + c * 2);
  float4 lw1 = *(const float4*)(lin_w + c * 2 + 4);
  float p0 = o0 * lw0.x + o1 * lw0.z + o2 * lw1.x + o3 * lw1.z;
  float p1 = o0 * lw0.y + o1 * lw0.w + o2 * lw1.y + o3 * lw1.w;
  p0 = wsum64(p0) * 0.25f;  // each dim-partial appears in 4 lane-groups
  p1 = wsum64(p1) * 0.25f;
  if (lane == 0) {
    out[n * 2 + 0] = p0 + lin_b[0];
    out[n * 2 + 1] = p1 + lin_b[1];
  }
}

// ---------------- launch ----------------
extern "C" void kernel_launch(void* const* d_in, const int* in_sizes, int n_in,
                              void* d_out, int out_size, void* d_ws, size_t ws_size,
                              hipStream_t stream) {
  const float* x      = (const float*)d_in[0];
  const int*   ei     = (const int*)d_in[1];
  const float* W1     = (const float*)d_in[2];
  const float* a_src1 = (const float*)d_in[3];
  const float* a_dst1 = (const float*)d_in[4];
  const float* b1     = (const float*)d_in[5];
  const float* W2     = (const float*)d_in[6];
  const float* a_src2 = (const float*)d_in[7];
  const float* a_dst2 = (const float*)d_in[8];
  const float* b2     = (const float*)d_in[9];
  const float* lin_w  = (const float*)d_in[10];
  const float* lin_b  = (const float*)d_in[11];
  float* outp = (float*)d_out;

  // Workspace layout (peak ~149.7 MB; previous sessions used 153.65 MB OK).
  // Live intervals: ebuf pass1->pass2 (inside agg slot, dead before agg written);
  // xh pass1->agg1; agg agg1->gemmAgg2; h2h gemmAgg2->attn2 (reuses xh slot);
  // csr pass2->attn2.
  char* w = (char*)d_ws;
  _Float16* agg  = (_Float16*)(w + 0);             // 102,432,768 (100,032 x 1KB, padded)
  unsigned* ebuf = (unsigned*)(w + 33554432);      // 16,777,216 (inside agg slot)
  _Float16* xh   = (_Float16*)(w + 102432768);     // 25,600,000
  _Float16* h2h  = (_Float16*)(w + 102432768);     // 12,800,000 (reuses xh slot)
  int*    csr    = (int*)(w + 128032768);          // 16,777,216
  _Float16* W1t  = (_Float16*)(w + 144809984);     // 65,536
  _Float16* W2t  = (_Float16*)(w + 144875520);     // 32,768
  float*  as1    = (float*)(w + 144908288);        // 1,600,000
  float*  ad1    = (float*)(w + 146508288);        // 1,600,000
  float*  as2    = (float*)(w + 148108288);        // 400,000
  float*  ad2    = (float*)(w + 148508288);        // 400,000
  int*    offs   = (int*)(w + 148908288);          // 400,000
  int*    degarr = (int*)(w + 149308288);          // 400,000
  int*    ccur   = (int*)(w + 149708288);          // 1,024

  k_init<<<1, 256, 0, stream>>>(ccur);
  k_pass1<<<NB0 + 192 + PREPB, 256, 0, stream>>>(ei, ccur, ebuf, W1, W2, W1t, W2t,
                                                 x, a_src1, a_dst1, xh, as1, ad1);
  k_pass2<<<256, 256, 0, stream>>>(ebuf, ccur, offs, degarr, csr);

  // layer 1: aggregate fp16(x) rows (one 256 B row serves all 4 heads), then transform
  k_agg1<<<NN / 4, 256, 0, stream>>>(offs, degarr, csr, as1, ad1, xh, agg);
  k_gemmAgg2<<<1563, 256, 0, stream>>>(agg, W1t, W2t, b1, a_src2, a_dst2, h2h, as2, ad2);

  // layer 2 attention + final linear
  k_attn2<<<NN / 4, 256, 0, stream>>>(offs, degarr, csr, as2, ad2, h2h, b2, lin_w, lin_b, outp);
}

// Round 5
// 551.666 us; speedup vs baseline: 1.2863x; 1.0771x over previous
//
#include <hip/hip_runtime.h>
#include <hip/hip_fp16.h>
#include <math.h>

#define NN 100000
#define EE 3200000
#define ETOT (EE + NN)
#define NEG_SLOPE 0.2f
#define DMAX 96
#define CHUNK 4096
#define NB0 ((ETOT + CHUNK - 1) / CHUNK)  // 806
#define RB 391                            // 256 * 391 >= NN
#define CAP 16384                         // window per coarse bucket (expect ~12.9k, sigma ~114)
#define PREPB 391                         // xh/as1/ad1 prep blocks appended to pass1

typedef _Float16 half8 __attribute__((ext_vector_type(8)));
typedef _Float16 half4v __attribute__((ext_vector_type(4)));
typedef _Float16 half2v __attribute__((ext_vector_type(2)));
typedef float floatx4 __attribute__((ext_vector_type(4)));

// ---------------- helpers ----------------
__device__ __forceinline__ float wsum64(float v) {
#pragma unroll
  for (int o = 32; o; o >>= 1) v += __shfl_xor(v, o);
  return v;
}
__device__ __forceinline__ float lrelu(float v) { return v > 0.f ? v : NEG_SLOPE * v; }
__device__ __forceinline__ float elu1(float v) { return v > 0.f ? v : expm1f(v); }

// ---------------- init: window cursors ----------------
__global__ void k_init(int* __restrict__ ccur) {
  ccur[threadIdx.x] = threadIdx.x * CAP;
}

// ---------------- pass1: edge bucketize + weight prep + xh/as1/ad1 prep ----------------
// blocks [0,NB0): bucketize; [NB0,NB0+192): W1t/W2t fp16 transposes;
// [NB0+192, NB0+192+PREPB): xh = fp16(x), as1/ad1 = x . (W1^T a) per head (exact by linearity).
__global__ __launch_bounds__(256) void k_pass1(const int* __restrict__ ei,
                                               int* __restrict__ ccur,
                                               unsigned* __restrict__ ebuf,
                                               const float* __restrict__ W1,
                                               const float* __restrict__ W2,
                                               _Float16* __restrict__ W1t,
                                               _Float16* __restrict__ W2t,
                                               const float* __restrict__ x,
                                               const float* __restrict__ a_src1,
                                               const float* __restrict__ a_dst1,
                                               _Float16* __restrict__ xh,
                                               float* __restrict__ as1,
                                               float* __restrict__ ad1) {
  __shared__ __align__(16) char smem[26624];
  const int b = blockIdx.x;
  const int t = threadIdx.x;
  if (b < NB0) {
    unsigned* vv = (unsigned*)smem;                        // 16384 B
    unsigned short* cbv = (unsigned short*)(smem + 16384); // 8192 B
    int* h = (int*)(smem + 24576);                         // 1024 B
    int* cur = (int*)(smem + 25600);                       // 1024 B
    h[t] = 0;
    __syncthreads();
    int base = b * CHUNK;
    int lim = base + CHUNK; if (lim > ETOT) lim = ETOT;
    int cnt = lim - base;
    for (int i = t; i < cnt; i += 256) {
      int e = base + i;
      int s, d;
      if (e < EE) { s = ei[e]; d = ei[EE + e]; } else { s = e - EE; d = s; }
      unsigned cb = (unsigned)d / (unsigned)RB;
      unsigned dloc = (unsigned)d - cb * (unsigned)RB;
      vv[i] = (dloc << 17) | (unsigned)s;
      cbv[i] = (unsigned short)cb;
      atomicAdd(&h[cb], 1);
    }
    __syncthreads();
    if (h[t]) cur[t] = atomicAdd(&ccur[t], h[t]);
    __syncthreads();
    for (int i = t; i < cnt; i += 256) {
      int cb = cbv[i];
      int pos = atomicAdd(&cur[cb], 1);
      ebuf[pos] = vv[i];
    }
    return;
  }
  if (b < NB0 + 192) {
    // weight prep: W1t[n][k] = W1[k][n] (32768), W2t[n][k] = W2[k][n] (16384)
    int idx = (b - NB0) * 256 + t;
    if (idx < 32768) {
      int n = idx >> 7, k = idx & 127;
      W1t[idx] = (_Float16)W1[k * 256 + n];
    } else {
      int j = idx - 32768;
      int n = j >> 8, k = j & 255;
      W2t[j] = (_Float16)W2[k * 64 + n];
    }
    return;
  }
  // ---- prep: vs/vd = W1^T a (per head), then per-node xh + as1/ad1 ----
  float* vs = (float*)smem;        // 512 floats
  float* vd = vs + 512;            // 512 floats
  for (int i = t; i < 512; i += 256) {
    int h = i >> 7, k = i & 127;
    const float* wrow = W1 + (size_t)k * 256 + h * 64;
    float ss = 0.f, dd = 0.f;
#pragma unroll 8
    for (int d2 = 0; d2 < 64; ++d2) {
      float wv = wrow[d2];
      ss = fmaf(wv, a_src1[h * 64 + d2], ss);
      dd = fmaf(wv, a_dst1[h * 64 + d2], dd);
    }
    vs[i] = ss; vd[i] = dd;
  }
  __syncthreads();
  const int lane = t & 63;
  const int gw = (b - NB0 - 192) * 4 + (t >> 6);  // 0 .. 4*PREPB-1
  for (int n = gw; n < NN; n += 4 * PREPB) {
    float2 xv = *(const float2*)(x + (size_t)n * 128 + lane * 2);
    half2v hx; hx[0] = (_Float16)xv.x; hx[1] = (_Float16)xv.y;
    *(half2v*)(xh + (size_t)n * 128 + lane * 2) = hx;
    float p[8];
#pragma unroll
    for (int h = 0; h < 4; ++h) {
      p[h]     = xv.x * vs[h * 128 + lane * 2] + xv.y * vs[h * 128 + lane * 2 + 1];
      p[4 + h] = xv.x * vd[h * 128 + lane * 2] + xv.y * vd[h * 128 + lane * 2 + 1];
    }
#pragma unroll
    for (int j = 0; j < 8; ++j) p[j] = wsum64(p[j]);
    if (lane == 0) {
      *(float4*)(as1 + n * 4) = make_float4(p[0], p[1], p[2], p[3]);
      *(float4*)(ad1 + n * 4) = make_float4(p[4], p[5], p[6], p[7]);
    }
  }
}

// ---------------- pass2: per-bucket exact placement via LDS cursors; emits offs+deg+csr ----
__global__ __launch_bounds__(256) void k_pass2(const unsigned* __restrict__ ebuf,
                                               const int* __restrict__ ccur,
                                               int* __restrict__ offs,
                                               int* __restrict__ degarr,
                                               int* __restrict__ csr) {
  __shared__ unsigned ed[CAP];
  __shared__ int hist[RB];
  __shared__ int cur[RB];
  int b = blockIdx.x, t = threadIdx.x;
  int d0 = b * RB;
  int rb = NN - d0; if (rb > RB) rb = RB;
  int w0 = b * CAP;
  int cnt = ccur[b] - w0;
  if (cnt > CAP) cnt = CAP;  // statistical impossibility guard
  for (int j = t; j < rb; j += 256) hist[j] = 0;
  __syncthreads();
  for (int i = t; i < cnt; i += 256) {
    unsigned v = ebuf[w0 + i];
    ed[i] = v;
    atomicAdd(&hist[v >> 17], 1);
  }
  __syncthreads();
  if (t == 0) {
    int run = w0;
    for (int j = 0; j < rb; ++j) { cur[j] = run; run += hist[j]; }
  }
  __syncthreads();
  for (int j = t; j < rb; j += 256) {
    offs[d0 + j] = cur[j];
    degarr[d0 + j] = hist[j];
  }
  __syncthreads();
  for (int i = t; i < cnt; i += 256) {
    unsigned v = ed[i];
    int pos = atomicAdd(&cur[v >> 17], 1);
    csr[pos] = (int)(v & 0x1FFFFu);
  }
}

// ---------------- fused layer1: softmax-aggregate + GEMM1 + elu + GEMM2 + as2/ad2 ------
// Block = 4 waves = 16 dst nodes. Phase A: each wave gathers/aggregates 4 dst (verified
// agg1 body) into LDS aggT[16][512]. Phase B: wave w applies W1 head w (MFMA) + bias +
// elu -> h1eT[16][256]. Phase C: wave w computes h2 cols [w*16,w*16+16) (MFMA) + as2/ad2.
// agg never touches HBM; W1t/W2t are L2-hot broadcast reads.
__global__ __launch_bounds__(256) void k_fused1(const int* __restrict__ offs,
                                                const int* __restrict__ degarr,
                                                const int* __restrict__ csr_src,
                                                const float* __restrict__ a_s,
                                                const float* __restrict__ a_d,
                                                const _Float16* __restrict__ xh,
                                                const _Float16* __restrict__ W1t,
                                                const _Float16* __restrict__ W2t,
                                                const float* __restrict__ b1,
                                                const float* __restrict__ a_src2,
                                                const float* __restrict__ a_dst2,
                                                _Float16* __restrict__ h2h,
                                                float* __restrict__ as_out,
                                                float* __restrict__ ad_out) {
  __shared__ __align__(16) float alp[4][DMAX][4];
  __shared__ int sidx[4][DMAX];
  __shared__ __align__(16) _Float16 aggT[16][520];   // 16 dst x 512 (+8 pad)
  __shared__ __align__(16) _Float16 h1eT[16][264];   // 16 dst x 256 (+8 pad)
  __shared__ float prt[2][4][16];                    // as2/ad2 partials
  const int wid = threadIdx.x >> 6;
  const int lane = threadIdx.x & 63;
  const int n0 = blockIdx.x * 16;
  const int g = lane >> 4;       // edge group / quad 0..3
  const int sub = lane & 15;     // dim sub-block / m16
  const _Float16* __restrict__ hb = xh + sub * 8;

  // ---------- phase A: aggregate 4 dst per wave ----------
  for (int dn = 0; dn < 4; ++dn) {
    const int n = n0 + wid * 4 + dn;
    const int beg = offs[n], deg = degarr[n];
    const float4 ad = *(const float4*)(a_d + n * 4);
    float4 sm = make_float4(0.f, 0.f, 0.f, 0.f);
    for (int d = lane; d < deg; d += 64) {
      int s = csr_src[beg + d];
      float4 as = *(const float4*)(a_s + s * 4);
      float e0 = __expf(lrelu(as.x + ad.x));
      float e1 = __expf(lrelu(as.y + ad.y));
      float e2 = __expf(lrelu(as.z + ad.z));
      float e3 = __expf(lrelu(as.w + ad.w));
      sm.x += e0; sm.y += e1; sm.z += e2; sm.w += e3;
      if (d < DMAX) {
        sidx[wid][d] = s;
        *(float4*)&alp[wid][d][0] = make_float4(e0, e1, e2, e3);
      }
    }
    sm.x = wsum64(sm.x); sm.y = wsum64(sm.y); sm.z = wsum64(sm.z); sm.w = wsum64(sm.w);
    const float4 inv4 = make_float4(1.f / sm.x, 1.f / sm.y, 1.f / sm.z, 1.f / sm.w);
    const int dlim = deg < DMAX ? deg : DMAX;
    for (int d = lane; d < dlim; d += 64) {
      float4 a = *(float4*)&alp[wid][d][0];
      a.x *= inv4.x; a.y *= inv4.y; a.z *= inv4.z; a.w *= inv4.w;
      *(float4*)&alp[wid][d][0] = a;
    }
    float acc[4][8];
#pragma unroll
    for (int h = 0; h < 4; ++h)
#pragma unroll
      for (int j = 0; j < 8; ++j) acc[h][j] = 0.f;
    int d = 0;
    for (; d + 8 <= dlim; d += 8) {
      int i0 = d + g, i1 = d + 4 + g;
      int s0 = sidx[wid][i0], s1 = sidx[wid][i1];
      float4 w0 = *(float4*)&alp[wid][i0][0];
      float4 w1 = *(float4*)&alp[wid][i1][0];
      half8 r0 = *(const half8*)(hb + (size_t)s0 * 128);
      half8 r1 = *(const half8*)(hb + (size_t)s1 * 128);
#pragma unroll
      for (int j = 0; j < 8; ++j) {
        float f0 = (float)r0[j], f1 = (float)r1[j];
        acc[0][j] = fmaf(f0, w0.x, acc[0][j]);
        acc[1][j] = fmaf(f0, w0.y, acc[1][j]);
        acc[2][j] = fmaf(f0, w0.z, acc[2][j]);
        acc[3][j] = fmaf(f0, w0.w, acc[3][j]);
        acc[0][j] = fmaf(f1, w1.x, acc[0][j]);
        acc[1][j] = fmaf(f1, w1.y, acc[1][j]);
        acc[2][j] = fmaf(f1, w1.z, acc[2][j]);
        acc[3][j] = fmaf(f1, w1.w, acc[3][j]);
      }
    }
    if (d + 4 <= dlim) {
      int i0 = d + g;
      int s0 = sidx[wid][i0];
      float4 w0 = *(float4*)&alp[wid][i0][0];
      half8 r0 = *(const half8*)(hb + (size_t)s0 * 128);
#pragma unroll
      for (int j = 0; j < 8; ++j) {
        float f0 = (float)r0[j];
        acc[0][j] = fmaf(f0, w0.x, acc[0][j]);
        acc[1][j] = fmaf(f0, w0.y, acc[1][j]);
        acc[2][j] = fmaf(f0, w0.z, acc[2][j]);
        acc[3][j] = fmaf(f0, w0.w, acc[3][j]);
      }
      d += 4;
    }
    if (d < dlim) {  // remainder 1..3 edges: inactive groups get weight 0
      int idx = d + g;
      bool v = idx < dlim;
      int s = sidx[wid][v ? idx : d];
      float4 w0 = *(float4*)&alp[wid][v ? idx : d][0];
      if (!v) { w0.x = 0.f; w0.y = 0.f; w0.z = 0.f; w0.w = 0.f; }
      half8 r0 = *(const half8*)(hb + (size_t)s * 128);
#pragma unroll
      for (int j = 0; j < 8; ++j) {
        float f0 = (float)r0[j];
        acc[0][j] = fmaf(f0, w0.x, acc[0][j]);
        acc[1][j] = fmaf(f0, w0.y, acc[1][j]);
        acc[2][j] = fmaf(f0, w0.z, acc[2][j]);
        acc[3][j] = fmaf(f0, w0.w, acc[3][j]);
      }
    }
    if (deg > DMAX) {  // overflow fallback: never in practice
      for (int dd = DMAX + g; dd < deg; dd += 4) {
        int s = csr_src[beg + dd];
        float4 as = *(const float4*)(a_s + s * 4);
        float w0x = __expf(lrelu(as.x + ad.x)) * inv4.x;
        float w0y = __expf(lrelu(as.y + ad.y)) * inv4.y;
        float w0z = __expf(lrelu(as.z + ad.z)) * inv4.z;
        float w0w = __expf(lrelu(as.w + ad.w)) * inv4.w;
        half8 r0 = *(const half8*)(hb + (size_t)s * 128);
#pragma unroll
        for (int j = 0; j < 8; ++j) {
          float f0 = (float)r0[j];
          acc[0][j] = fmaf(f0, w0x, acc[0][j]);
          acc[1][j] = fmaf(f0, w0y, acc[1][j]);
          acc[2][j] = fmaf(f0, w0z, acc[2][j]);
          acc[3][j] = fmaf(f0, w0w, acc[3][j]);
        }
      }
    }
    // reduce across 4 edge-groups; g==0 lanes hold the final row slice
#pragma unroll
    for (int h = 0; h < 4; ++h)
#pragma unroll
      for (int j = 0; j < 8; ++j) {
        acc[h][j] += __shfl_xor(acc[h][j], 16);
        acc[h][j] += __shfl_xor(acc[h][j], 32);
      }
    if (g == 0) {
#pragma unroll
      for (int h = 0; h < 4; ++h) {
        half8 o;
#pragma unroll
        for (int j = 0; j < 8; ++j) o[j] = (_Float16)acc[h][j];
        *(half8*)&aggT[wid * 4 + dn][h * 128 + sub * 8] = o;
      }
    }
  }
  __syncthreads();

  // ---------- phase B: GEMM1 head wid: [16x128] @ [128x64] + bias + elu ----------
  const int m16 = sub, quad = g;
  floatx4 acc1[4];
#pragma unroll
  for (int nt = 0; nt < 4; ++nt) acc1[nt] = (floatx4){0.f, 0.f, 0.f, 0.f};
#pragma unroll
  for (int ks = 0; ks < 4; ++ks) {
    half8 av = *(half8*)&aggT[m16][wid * 128 + ks * 32 + quad * 8];
#pragma unroll
    for (int nt = 0; nt < 4; ++nt) {
      half8 bv = *(const half8*)(W1t + (size_t)(wid * 64 + nt * 16 + m16) * 128 + ks * 32 + quad * 8);
      acc1[nt] = __builtin_amdgcn_mfma_f32_16x16x32_f16(av, bv, acc1[nt], 0, 0, 0);
    }
  }
#pragma unroll
  for (int nt = 0; nt < 4; ++nt) {
    float bb = b1[wid * 64 + nt * 16 + m16];
#pragma unroll
    for (int r = 0; r < 4; ++r)
      h1eT[quad * 4 + r][wid * 64 + nt * 16 + m16] = (_Float16)elu1(acc1[nt][r] + bb);
  }
  __syncthreads();

  // ---------- phase C: GEMM2 col-block wid: [16x256] @ [256x16] + as2/ad2 ----------
  floatx4 acc2 = (floatx4){0.f, 0.f, 0.f, 0.f};
#pragma unroll
  for (int ks = 0; ks < 8; ++ks) {
    half8 av = *(half8*)&h1eT[m16][ks * 32 + quad * 8];
    half8 bv = *(const half8*)(W2t + (size_t)(wid * 16 + m16) * 256 + ks * 32 + quad * 8);
    acc2 = __builtin_amdgcn_mfma_f32_16x16x32_f16(av, bv, acc2, 0, 0, 0);
  }
  const float a2v = a_src2[wid * 16 + m16];
  const float d2v = a_dst2[wid * 16 + m16];
#pragma unroll
  for (int r = 0; r < 4; ++r) {
    int row = quad * 4 + r;
    h2h[(size_t)(n0 + row) * 64 + wid * 16 + m16] = (_Float16)acc2[r];
    float ps = acc2[r] * a2v, pd = acc2[r] * d2v;
#pragma unroll
    for (int o = 1; o < 16; o <<= 1) { ps += __shfl_xor(ps, o); pd += __shfl_xor(pd, o); }
    if (m16 == 0) { prt[0][wid][row] = ps; prt[1][wid][row] = pd; }
  }
  __syncthreads();
  if (threadIdx.x < 16) {
    int row = threadIdx.x;
    as_out[n0 + row] = prt[0][0][row] + prt[0][1][row] + prt[0][2][row] + prt[0][3][row];
    ad_out[n0 + row] = prt[1][0][row] + prt[1][1][row] + prt[1][2][row] + prt[1][3][row];
  }
}

// ---------------- fused attention layer 2 + final linear ----------------
__global__ __launch_bounds__(256) void k_attn2(const int* __restrict__ offs,
                                               const int* __restrict__ degarr,
                                               const int* __restrict__ csr_src,
                                               const float* __restrict__ a_s,
                                               const float* __restrict__ a_d,
                                               const _Float16* __restrict__ h2h,
                                               const float* __restrict__ b2,
                                               const float* __restrict__ lin_w,
                                               const float* __restrict__ lin_b,
                                               float* __restrict__ out) {
  __shared__ float alpha2[4][DMAX];
  __shared__ int sidx2[4][DMAX];
  const int wid = threadIdx.x >> 6;
  const int n = blockIdx.x * 4 + wid;
  const int lane = threadIdx.x & 63;
  const int beg = offs[n], deg = degarr[n];
  const float adn = a_d[n];
  float sm = 0.f;
  for (int d = lane; d < deg; d += 64) {
    int s = csr_src[beg + d];
    float e = __expf(lrelu(a_s[s] + adn));
    sm += e;
    if (d < DMAX) { sidx2[wid][d] = s; alpha2[wid][d] = e; }
  }
  sm = wsum64(sm);
  const float inv = 1.f / sm;
  const int dlim = deg < DMAX ? deg : DMAX;
  for (int d = lane; d < dlim; d += 64) alpha2[wid][d] *= inv;
  const int g = lane >> 4;       // edge group 0..3
  const int sub = lane & 15;     // dims sub*4 .. sub*4+3
  const _Float16* __restrict__ hb = h2h + sub * 4;
  float a0 = 0.f, a1 = 0.f, a2 = 0.f, a3 = 0.f;
  int d = 0;
  for (; d + 8 <= dlim; d += 8) {
    int i0 = d + g, i1 = d + 4 + g;
    int s0 = sidx2[wid][i0], s1 = sidx2[wid][i1];
    float w0 = alpha2[wid][i0], w1 = alpha2[wid][i1];
    half4v r0 = *(const half4v*)(hb + (size_t)s0 * 64);
    half4v r1 = *(const half4v*)(hb + (size_t)s1 * 64);
    a0 = fmaf((float)r0[0], w0, a0); a1 = fmaf((float)r0[1], w0, a1);
    a2 = fmaf((float)r0[2], w0, a2); a3 = fmaf((float)r0[3], w0, a3);
    a0 = fmaf((float)r1[0], w1, a0); a1 = fmaf((float)r1[1], w1, a1);
    a2 = fmaf((float)r1[2], w1, a2); a3 = fmaf((float)r1[3], w1, a3);
  }
  if (d + 4 <= dlim) {
    int i0 = d + g;
    int s0 = sidx2[wid][i0];
    float w0 = alpha2[wid][i0];
    half4v r0 = *(const half4v*)(hb + (size_t)s0 * 64);
    a0 = fmaf((float)r0[0], w0, a0); a1 = fmaf((float)r0[1], w0, a1);
    a2 = fmaf((float)r0[2], w0, a2); a3 = fmaf((float)r0[3], w0, a3);
    d += 4;
  }
  if (d < dlim) {  // remainder 1..3 edges: inactive groups get weight 0
    int idx = d + g;
    bool v = idx < dlim;
    int s = sidx2[wid][v ? idx : d];
    float w = v ? alpha2[wid][idx] : 0.f;
    half4v r = *(const half4v*)(hb + (size_t)s * 64);
    a0 = fmaf((float)r[0], w, a0); a1 = fmaf((float)r[1], w, a1);
    a2 = fmaf((float)r[2], w, a2); a3 = fmaf((float)r[3], w, a3);
  }
  if (deg > DMAX && g == 0) {  // overflow fallback: never in practice
    for (int dd = DMAX; dd < deg; ++dd) {
      int s = csr_src[beg + dd];
      float w = __expf(lrelu(a_s[s] + adn)) * inv;
      half4v r = *(const half4v*)(hb + (size_t)s * 64);
      a0 = fmaf((float)r[0], w, a0); a1 = fmaf((float)r[1], w, a1);
      a2 = fmaf((float)r[2], w, a2); a3 = fmaf((float)r[3], w, a3);
    }
  }
  // combine the 4 edge-groups (lane bits 4 and 5)
  a0 += __shfl_xor(a0, 16); a1 += __shfl_xor(a1, 16);
  a2 += __shfl_xor(a2, 16); a3 += __shfl_xor(a3, 16);
  a0 += __shfl_xor(a0, 32); a1 += __shfl_xor(a1, 32);
  a2 += __shfl_xor(a2, 32); a3 += __shfl_xor(a3, 32);
  const int c = sub * 4;
  float4 bb = *(const float4*)(b2 + c);
  float o0 = elu1(a0 + bb.x);
  float o1 = elu1(a1 + bb.y);
  float o2 = elu1(a2 + bb.z);
  float o3 = elu1(a3 + bb.w);
  float4 lw0 = *(const float4*)(lin_w + c * 2);
  float4 lw1 = *(const float4*)(lin_w + c * 2 + 4);
  float p0 = o0 * lw0.x + o1 * lw0.z + o2 * lw1.x + o3 * lw1.z;
  float p1 = o0 * lw0.y + o1 * lw0.w + o2 * lw1.y + o3 * lw1.w;
  p0 = wsum64(p0) * 0.25f;  // each dim-partial appears in 4 lane-groups
  p1 = wsum64(p1) * 0.25f;
  if (lane == 0) {
    out[n * 2 + 0] = p0 + lin_b[0];
    out[n * 2 + 1] = p1 + lin_b[1];
  }
}

// ---------------- launch ----------------
extern "C" void kernel_launch(void* const* d_in, const int* in_sizes, int n_in,
                              void* d_out, int out_size, void* d_ws, size_t ws_size,
                              hipStream_t stream) {
  const float* x      = (const float*)d_in[0];
  const int*   ei     = (const int*)d_in[1];
  const float* W1     = (const float*)d_in[2];
  const float* a_src1 = (const float*)d_in[3];
  const float* a_dst1 = (const float*)d_in[4];
  const float* b1     = (const float*)d_in[5];
  const float* W2     = (const float*)d_in[6];
  const float* a_src2 = (const float*)d_in[7];
  const float* a_dst2 = (const float*)d_in[8];
  const float* b2     = (const float*)d_in[9];
  const float* lin_w  = (const float*)d_in[10];
  const float* lin_b  = (const float*)d_in[11];
  float* outp = (float*)d_out;

  // Workspace (~78 MB, no overlaps). Live intervals all disjoint or compatible.
  char* w = (char*)d_ws;
  _Float16* xh   = (_Float16*)(w + 0);             // 25,600,000
  _Float16* h2h  = (_Float16*)(w + 25600000);      // 12,800,000
  unsigned* ebuf = (unsigned*)(w + 38400000);      // 16,777,216
  int*    csr    = (int*)(w + 55177216);           // 16,777,216
  _Float16* W1t  = (_Float16*)(w + 71954432);      // 65,536
  _Float16* W2t  = (_Float16*)(w + 72019968);      // 32,768
  float*  as1    = (float*)(w + 72052736);         // 1,600,000
  float*  ad1    = (float*)(w + 73652736);         // 1,600,000
  float*  as2    = (float*)(w + 75252736);         // 400,000
  float*  ad2    = (float*)(w + 75652736);         // 400,000
  int*    offs   = (int*)(w + 76052736);           // 400,000
  int*    degarr = (int*)(w + 76452736);           // 400,000
  int*    ccur   = (int*)(w + 76852736);           // 1,024

  k_init<<<1, 256, 0, stream>>>(ccur);
  k_pass1<<<NB0 + 192 + PREPB, 256, 0, stream>>>(ei, ccur, ebuf, W1, W2, W1t, W2t,
                                                 x, a_src1, a_dst1, xh, as1, ad1);
  k_pass2<<<256, 256, 0, stream>>>(ebuf, ccur, offs, degarr, csr);

  // layer 1 fused: aggregate + transform (no agg materialization)
  k_fused1<<<NN / 16, 256, 0, stream>>>(offs, degarr, csr, as1, ad1, xh,
                                        W1t, W2t, b1, a_src2, a_dst2, h2h, as2, ad2);

  // layer 2 attention + final linear
  k_attn2<<<NN / 4, 256, 0, stream>>>(offs, degarr, csr, as2, ad2, h2h, b2, lin_w, lin_b, outp);
}